// Round 1
// baseline (646.546 us; speedup 1.0000x reference)
//
#include <hip/hip_runtime.h>
#include <stdint.h>

typedef unsigned short u16;
typedef __attribute__((ext_vector_type(8))) short bf16x8;
typedef __attribute__((ext_vector_type(4))) float f32x4;

__device__ __forceinline__ u16 f2bf(float f) {
    union { float f; uint32_t u; } v; v.f = f;
    uint32_t r = (v.u + 0x7FFFu + ((v.u >> 16) & 1u)) >> 16;
    return (u16)r;
}

// ---------------- fp32 -> bf16 convert (weights) ----------------
__global__ __launch_bounds__(256) void cvt_kernel(const float* __restrict__ in,
                                                  u16* __restrict__ out, int n4) {
    int i = blockIdx.x * 256 + threadIdx.x;
    if (i < n4) {
        float4 v = ((const float4*)in)[i];
        uint2 o;
        o.x = (uint32_t)f2bf(v.x) | ((uint32_t)f2bf(v.y) << 16);
        o.y = (uint32_t)f2bf(v.z) | ((uint32_t)f2bf(v.w) << 16);
        ((uint2*)out)[i] = o;
    }
}

// ---------------- LayerNorm (fp32 in, bf16 out), D=1024 ----------------
__global__ __launch_bounds__(256) void ln_kernel(const float* __restrict__ x,
                                                 const float* __restrict__ g,
                                                 const float* __restrict__ beta,
                                                 u16* __restrict__ out) {
    int row = blockIdx.x;
    int tid = threadIdx.x;
    const float4 v = ((const float4*)(x + (size_t)row * 1024))[tid];
    float s  = v.x + v.y + v.z + v.w;
    float sq = v.x*v.x + v.y*v.y + v.z*v.z + v.w*v.w;
    #pragma unroll
    for (int off = 32; off; off >>= 1) {
        s  += __shfl_xor(s,  off, 64);
        sq += __shfl_xor(sq, off, 64);
    }
    __shared__ float rs[4], rq[4];
    int w = tid >> 6;
    if ((tid & 63) == 0) { rs[w] = s; rq[w] = sq; }
    __syncthreads();
    s  = rs[0] + rs[1] + rs[2] + rs[3];
    sq = rq[0] + rq[1] + rq[2] + rq[3];
    float mu   = s * (1.0f / 1024.0f);
    float var  = sq * (1.0f / 1024.0f) - mu * mu;
    float rstd = rsqrtf(var + 1e-6f);
    float4 gv = ((const float4*)g)[tid];
    float4 bv = ((const float4*)beta)[tid];
    uint2 o;
    o.x = (uint32_t)f2bf((v.x - mu) * rstd * gv.x + bv.x) |
          ((uint32_t)f2bf((v.y - mu) * rstd * gv.y + bv.y) << 16);
    o.y = (uint32_t)f2bf((v.z - mu) * rstd * gv.z + bv.z) |
          ((uint32_t)f2bf((v.w - mu) * rstd * gv.w + bv.w) << 16);
    ((uint2*)(out + (size_t)row * 1024))[tid] = o;
}

// ---------------- GEMM: C[M,N] = A[M,K](bf16) * W[N,K](bf16)^T + bias (+res)(+gelu) ----
// 128x128 tile, BK=64, 4 waves (2x2), mfma_f32_16x16x32_bf16
template<int ACT, int RES, int OUTBF>
__global__ __launch_bounds__(256) void gemm_kernel(
    const u16* __restrict__ A, const u16* __restrict__ W,
    const float* __restrict__ bias, const float* __restrict__ res,
    void* __restrict__ Cout, int M, int N, int K)
{
    const int LDT = 72;  // 64 + 8 pad: 144B rows, 16B-aligned, 2-way banks
    __shared__ u16 sA[128 * LDT];
    __shared__ u16 sB[128 * LDT];
    int tid = threadIdx.x;
    int lane = tid & 63, wid = tid >> 6;
    int wm = wid >> 1, wn = wid & 1;
    int ntiles = N >> 7;
    int m0 = (blockIdx.x / ntiles) << 7;
    int n0 = (blockIdx.x % ntiles) << 7;
    int q = lane & 15, g = lane >> 4;

    f32x4 acc[4][4];
    #pragma unroll
    for (int i = 0; i < 4; i++)
        #pragma unroll
        for (int j = 0; j < 4; j++)
            acc[i][j] = (f32x4){0.f, 0.f, 0.f, 0.f};

    for (int k0 = 0; k0 < K; k0 += 64) {
        __syncthreads();
        #pragma unroll
        for (int p = 0; p < 4; p++) {
            int flat = (p * 256 + tid) * 8;
            int r = flat >> 6, c = flat & 63;
            uint4 av = *(const uint4*)(A + (size_t)(m0 + r) * K + k0 + c);
            *(uint4*)(sA + r * LDT + c) = av;
            uint4 bv = *(const uint4*)(W + (size_t)(n0 + r) * K + k0 + c);
            *(uint4*)(sB + r * LDT + c) = bv;
        }
        __syncthreads();
        #pragma unroll
        for (int ks = 0; ks < 2; ks++) {
            bf16x8 af[4], bf[4];
            #pragma unroll
            for (int i = 0; i < 4; i++) {
                af[i] = *(const bf16x8*)(sA + (wm * 64 + i * 16 + q) * LDT + ks * 32 + g * 8);
                bf[i] = *(const bf16x8*)(sB + (wn * 64 + i * 16 + q) * LDT + ks * 32 + g * 8);
            }
            #pragma unroll
            for (int i = 0; i < 4; i++)
                #pragma unroll
                for (int j = 0; j < 4; j++)
                    acc[i][j] = __builtin_amdgcn_mfma_f32_16x16x32_bf16(af[i], bf[j], acc[i][j], 0, 0, 0);
        }
    }

    #pragma unroll
    for (int i = 0; i < 4; i++) {
        #pragma unroll
        for (int j = 0; j < 4; j++) {
            int col = n0 + wn * 64 + j * 16 + q;
            float bz = bias[col];
            #pragma unroll
            for (int r = 0; r < 4; r++) {
                int row = m0 + wm * 64 + i * 16 + g * 4 + r;
                float v = acc[i][j][r] + bz;
                if (ACT == 1) v = 0.5f * v * (1.0f + erff(v * 0.70710678118654752f));
                if (RES) v += res[(size_t)row * N + col];
                if (OUTBF) ((u16*)Cout)[(size_t)row * N + col] = f2bf(v);
                else       ((float*)Cout)[(size_t)row * N + col] = v;
            }
        }
    }
}

// ---------------- Flash attention: qkv bf16 [B,S,3,H,HD] -> ctx bf16 [B,S,D] --------
// grid = B*H*(S/64); 4 waves/block, each wave owns a 16-row Q tile; 32-key KV tiles.
__global__ __launch_bounds__(256) void attn_kernel(const u16* __restrict__ qkv,
                                                   u16* __restrict__ ctx) {
    int bid = blockIdx.x;
    int qt = bid & 15;
    int h  = (bid >> 4) & 15;
    int b  = bid >> 8;
    int tid = threadIdx.x, lane = tid & 63, w = tid >> 6;
    int q = lane & 15, g = lane >> 4;

    __shared__ u16 sQ[64 * 72];
    __shared__ u16 sK[32 * 72];
    __shared__ u16 sVT[64 * 40];

    const size_t tokBase = ((size_t)b * 1024) * 3072 + (size_t)h * 64;

    #pragma unroll
    for (int p = 0; p < 2; p++) {
        int flat = (p * 256 + tid) * 8;
        int r = flat >> 6, c = flat & 63;
        uint4 v = *(const uint4*)(qkv + tokBase + (size_t)(qt * 64 + r) * 3072 + c);
        *(uint4*)(sQ + r * 72 + c) = v;
    }
    __syncthreads();
    bf16x8 qf0 = *(const bf16x8*)(sQ + (w * 16 + q) * 72 + g * 8);
    bf16x8 qf1 = *(const bf16x8*)(sQ + (w * 16 + q) * 72 + 32 + g * 8);

    float m_run = -1e30f, l_run = 0.0f;
    f32x4 o[4];
    #pragma unroll
    for (int n = 0; n < 4; n++) o[n] = (f32x4){0.f, 0.f, 0.f, 0.f};

    for (int kt = 0; kt < 32; kt++) {
        __syncthreads();
        {   // stage K tile [32][64]
            int r = tid >> 3, c = (tid & 7) * 8;
            uint4 v = *(const uint4*)(qkv + tokBase + (size_t)(kt * 32 + r) * 3072 + 1024 + c);
            *(uint4*)(sK + r * 72 + c) = v;
        }
        #pragma unroll
        for (int p = 0; p < 2; p++) {  // stage V^T [64][32]
            int flat = (p * 256 + tid) * 4;
            int key = flat >> 6, c = flat & 63;
            const u16* src = qkv + tokBase + (size_t)(kt * 32 + key) * 3072 + 2048 + c;
            #pragma unroll
            for (int j = 0; j < 4; j++) sVT[(c + j) * 40 + key] = src[j];
        }
        __syncthreads();

        // S' = K(32xHD) . Q^T  -> two 16-key score tiles (swapped operands)
        f32x4 s0 = (f32x4){0.f, 0.f, 0.f, 0.f}, s1 = s0;
        {
            bf16x8 k00 = *(const bf16x8*)(sK + (q) * 72 + g * 8);
            bf16x8 k01 = *(const bf16x8*)(sK + (q) * 72 + 32 + g * 8);
            s0 = __builtin_amdgcn_mfma_f32_16x16x32_bf16(k00, qf0, s0, 0, 0, 0);
            s0 = __builtin_amdgcn_mfma_f32_16x16x32_bf16(k01, qf1, s0, 0, 0, 0);
            bf16x8 k10 = *(const bf16x8*)(sK + (16 + q) * 72 + g * 8);
            bf16x8 k11 = *(const bf16x8*)(sK + (16 + q) * 72 + 32 + g * 8);
            s1 = __builtin_amdgcn_mfma_f32_16x16x32_bf16(k10, qf0, s1, 0, 0, 0);
            s1 = __builtin_amdgcn_mfma_f32_16x16x32_bf16(k11, qf1, s1, 0, 0, 0);
        }
        float ps[8];
        #pragma unroll
        for (int r = 0; r < 4; r++) { ps[r] = s0[r] * 0.125f; ps[4 + r] = s1[r] * 0.125f; }
        float tm = ps[0];
        #pragma unroll
        for (int i = 1; i < 8; i++) tm = fmaxf(tm, ps[i]);
        tm = fmaxf(tm, __shfl_xor(tm, 16, 64));
        tm = fmaxf(tm, __shfl_xor(tm, 32, 64));
        float nm = fmaxf(m_run, tm);
        float f = __expf(m_run - nm);
        float ts = 0.0f;
        #pragma unroll
        for (int i = 0; i < 8; i++) { ps[i] = __expf(ps[i] - nm); ts += ps[i]; }
        ts += __shfl_xor(ts, 16, 64);
        ts += __shfl_xor(ts, 32, 64);
        l_run = l_run * f + ts;
        m_run = nm;

        // rearrange P (lane holds keys 16*kh+4g+r for row q) into canonical A-frag order
        bf16x8 pf;
        #pragma unroll
        for (int j = 0; j < 8; j++) {
            int src = q + 16 * (2 * (g & 1) + (j >> 2));
            float a  = __shfl(ps[j & 3], src, 64);
            float bb = __shfl(ps[4 + (j & 3)], src, 64);
            float pv = (g >> 1) ? bb : a;
            pf[j] = (short)f2bf(pv);
        }
        // rescale O (rows of O are q = 4g+r; factors live at lane index q)
        float fr[4];
        #pragma unroll
        for (int r = 0; r < 4; r++) fr[r] = __shfl(f, g * 4 + r, 64);
        #pragma unroll
        for (int n = 0; n < 4; n++)
            #pragma unroll
            for (int r = 0; r < 4; r++) o[n][r] *= fr[r];
        // PV: one K=32 MFMA per 16-col block of HD
        #pragma unroll
        for (int n = 0; n < 4; n++) {
            bf16x8 vf = *(const bf16x8*)(sVT + (n * 16 + q) * 40 + g * 8);
            o[n] = __builtin_amdgcn_mfma_f32_16x16x32_bf16(pf, vf, o[n], 0, 0, 0);
        }
    }

    float inv = 1.0f / l_run;
    float ir[4];
    #pragma unroll
    for (int r = 0; r < 4; r++) ir[r] = __shfl(inv, g * 4 + r, 64);
    size_t outBase = ((size_t)b * 1024 + qt * 64 + w * 16) * 1024 + (size_t)h * 64;
    #pragma unroll
    for (int n = 0; n < 4; n++)
        #pragma unroll
        for (int r = 0; r < 4; r++)
            ctx[outBase + (size_t)(g * 4 + r) * 1024 + n * 16 + q] = f2bf(o[n][r] * ir[r]);
}

extern "C" void kernel_launch(void* const* d_in, const int* in_sizes, int n_in,
                              void* d_out, int out_size, void* d_ws, size_t ws_size,
                              hipStream_t stream) {
    const float* x      = (const float*)d_in[0];
    const float* qkv_w  = (const float*)d_in[1];
    const float* qkv_b  = (const float*)d_in[2];
    const float* proj_w = (const float*)d_in[3];
    const float* proj_b = (const float*)d_in[4];
    const float* fc1_w  = (const float*)d_in[5];
    const float* fc1_b  = (const float*)d_in[6];
    const float* fc2_w  = (const float*)d_in[7];
    const float* fc2_b  = (const float*)d_in[8];
    const float* ln1_g  = (const float*)d_in[9];
    const float* ln1_b  = (const float*)d_in[10];
    const float* ln2_g  = (const float*)d_in[11];
    const float* ln2_b  = (const float*)d_in[12];
    float* out = (float*)d_out;

    char* ws = (char*)d_ws;
    u16* wq = (u16*)(ws);               // qkv_w bf16: 3145728 elems
    u16* wp = (u16*)(ws + 6291456);     // proj_w bf16: 1048576
    u16* w1 = (u16*)(ws + 8388608);     // fc1_w bf16: 4194304
    u16* w2 = (u16*)(ws + 16777216);    // fc2_w bf16: 4194304
    char* pool = ws + 25165824;
    u16* hbuf = (u16*)(pool);                   // ln1 out bf16 [8192,1024]
    u16* qkvb = (u16*)(pool + 16777216);        // qkv bf16 [8192,3072]
    u16* ctxb = (u16*)(pool);                   // ctx bf16 (reuses hbuf, h dead)
    u16* h2b  = (u16*)(pool + 16777216);        // ln2 out bf16 (reuses qkv)
    u16* a1b  = (u16*)(pool + 33554432);        // gelu out bf16 [8192,4096]

    cvt_kernel<<<3072, 256, 0, stream>>>(qkv_w, wq, 786432);
    cvt_kernel<<<1024, 256, 0, stream>>>(proj_w, wp, 262144);
    cvt_kernel<<<4096, 256, 0, stream>>>(fc1_w, w1, 1048576);
    cvt_kernel<<<4096, 256, 0, stream>>>(fc2_w, w2, 1048576);

    ln_kernel<<<8192, 256, 0, stream>>>(x, ln1_g, ln1_b, hbuf);
    gemm_kernel<0,0,1><<<64 * 24, 256, 0, stream>>>(hbuf, wq, qkv_b, nullptr, qkvb, 8192, 3072, 1024);
    attn_kernel<<<2048, 256, 0, stream>>>(qkvb, ctxb);
    gemm_kernel<0,1,0><<<64 * 8, 256, 0, stream>>>(ctxb, wp, proj_b, x, out, 8192, 1024, 1024);
    ln_kernel<<<8192, 256, 0, stream>>>(out, ln2_g, ln2_b, h2b);
    gemm_kernel<1,0,1><<<64 * 32, 256, 0, stream>>>(h2b, w1, fc1_b, nullptr, a1b, 8192, 4096, 1024);
    gemm_kernel<0,1,0><<<64 * 8, 256, 0, stream>>>(a1b, w2, fc2_b, out, out, 8192, 1024, 4096);
}

// Round 2
// 591.085 us; speedup vs baseline: 1.0938x; 1.0938x over previous
//
#include <hip/hip_runtime.h>
#include <stdint.h>

typedef unsigned short u16;
typedef __attribute__((ext_vector_type(8))) short bf16x8;
typedef __attribute__((ext_vector_type(4))) short bf16x4;
typedef __attribute__((ext_vector_type(4))) float f32x4;

__device__ __forceinline__ u16 f2bf(float f) {
    union { float f; uint32_t u; } v; v.f = f;
    uint32_t r = (v.u + 0x7FFFu + ((v.u >> 16) & 1u)) >> 16;
    return (u16)r;
}

// async global->LDS, 16B per lane; lds base must be wave-uniform
__device__ __forceinline__ void g2l16(const u16* g, u16* l) {
    __builtin_amdgcn_global_load_lds(
        (const __attribute__((address_space(1))) uint32_t*)g,
        (__attribute__((address_space(3))) uint32_t*)l, 16, 0, 0);
}

// ---------------- fp32 -> bf16 convert (weights) ----------------
__global__ __launch_bounds__(256) void cvt_kernel(const float* __restrict__ in,
                                                  u16* __restrict__ out, int n4) {
    int i = blockIdx.x * 256 + threadIdx.x;
    if (i < n4) {
        float4 v = ((const float4*)in)[i];
        uint2 o;
        o.x = (uint32_t)f2bf(v.x) | ((uint32_t)f2bf(v.y) << 16);
        o.y = (uint32_t)f2bf(v.z) | ((uint32_t)f2bf(v.w) << 16);
        ((uint2*)out)[i] = o;
    }
}

// ---------------- LayerNorm (fp32 in, bf16 out), D=1024 ----------------
__global__ __launch_bounds__(256) void ln_kernel(const float* __restrict__ x,
                                                 const float* __restrict__ g,
                                                 const float* __restrict__ beta,
                                                 u16* __restrict__ out) {
    int row = blockIdx.x;
    int tid = threadIdx.x;
    const float4 v = ((const float4*)(x + (size_t)row * 1024))[tid];
    float s  = v.x + v.y + v.z + v.w;
    float sq = v.x*v.x + v.y*v.y + v.z*v.z + v.w*v.w;
    #pragma unroll
    for (int off = 32; off; off >>= 1) {
        s  += __shfl_xor(s,  off, 64);
        sq += __shfl_xor(sq, off, 64);
    }
    __shared__ float rs[4], rq[4];
    int w = tid >> 6;
    if ((tid & 63) == 0) { rs[w] = s; rq[w] = sq; }
    __syncthreads();
    s  = rs[0] + rs[1] + rs[2] + rs[3];
    sq = rq[0] + rq[1] + rq[2] + rq[3];
    float mu   = s * (1.0f / 1024.0f);
    float var  = sq * (1.0f / 1024.0f) - mu * mu;
    float rstd = rsqrtf(var + 1e-6f);
    float4 gv = ((const float4*)g)[tid];
    float4 bv = ((const float4*)beta)[tid];
    uint2 o;
    o.x = (uint32_t)f2bf((v.x - mu) * rstd * gv.x + bv.x) |
          ((uint32_t)f2bf((v.y - mu) * rstd * gv.y + bv.y) << 16);
    o.y = (uint32_t)f2bf((v.z - mu) * rstd * gv.z + bv.z) |
          ((uint32_t)f2bf((v.w - mu) * rstd * gv.w + bv.w) << 16);
    ((uint2*)(out + (size_t)row * 1024))[tid] = o;
}

// ---------------- GEMM: C[M,N] = A[M,K](bf16) * W[N,K](bf16)^T + bias (+res)(+gelu) ----
// m97 structure: 128x128 tile, BK=64, 4 waves (2x2), linear LDS, global_load_lds staging
template<int ACT, int RES, int OUTBF>
__global__ __launch_bounds__(256) void gemm_kernel(
    const u16* __restrict__ A, const u16* __restrict__ W,
    const float* __restrict__ bias, const float* __restrict__ res,
    void* __restrict__ Cout, int M, int N, int K)
{
    __shared__ u16 sA[128 * 64];
    __shared__ u16 sB[128 * 64];
    int tid = threadIdx.x;
    int lane = tid & 63, wid = tid >> 6;
    int wm = wid >> 1, wn = wid & 1;
    int ntiles = N >> 7;
    int m0 = (blockIdx.x / ntiles) << 7;
    int n0 = (blockIdx.x % ntiles) << 7;
    int q = lane & 15, g = lane >> 4;

    f32x4 acc[4][4];
    #pragma unroll
    for (int i = 0; i < 4; i++)
        #pragma unroll
        for (int j = 0; j < 4; j++)
            acc[i][j] = (f32x4){0.f, 0.f, 0.f, 0.f};

    for (int k0 = 0; k0 < K; k0 += 64) {
        __syncthreads();
        #pragma unroll
        for (int c = 0; c < 4; c++) {
            int flat = ((c * 4 + wid) * 64 + lane) * 8;  // elem idx in 128x64 tile
            int r = flat >> 6, cc = flat & 63;
            g2l16(A + (size_t)(m0 + r) * K + k0 + cc, sA + (c * 4 + wid) * 512);
            g2l16(W + (size_t)(n0 + r) * K + k0 + cc, sB + (c * 4 + wid) * 512);
        }
        __syncthreads();  // compiler emits vmcnt(0) drain before s_barrier
        #pragma unroll
        for (int ks = 0; ks < 2; ks++) {
            bf16x8 af[4], bfr[4];
            #pragma unroll
            for (int i = 0; i < 4; i++) {
                af[i]  = *(const bf16x8*)(sA + (wm * 64 + i * 16 + q) * 64 + ks * 32 + g * 8);
                bfr[i] = *(const bf16x8*)(sB + (wn * 64 + i * 16 + q) * 64 + ks * 32 + g * 8);
            }
            #pragma unroll
            for (int i = 0; i < 4; i++)
                #pragma unroll
                for (int j = 0; j < 4; j++)
                    acc[i][j] = __builtin_amdgcn_mfma_f32_16x16x32_bf16(af[i], bfr[j], acc[i][j], 0, 0, 0);
        }
    }

    #pragma unroll
    for (int i = 0; i < 4; i++) {
        #pragma unroll
        for (int j = 0; j < 4; j++) {
            int col = n0 + wn * 64 + j * 16 + q;
            float bz = bias[col];
            #pragma unroll
            for (int r = 0; r < 4; r++) {
                int row = m0 + wm * 64 + i * 16 + g * 4 + r;
                float v = acc[i][j][r] + bz;
                if (ACT == 1) v = 0.5f * v * (1.0f + erff(v * 0.70710678118654752f));
                if (RES) v += res[(size_t)row * N + col];
                if (OUTBF) ((u16*)Cout)[(size_t)row * N + col] = f2bf(v);
                else       ((float*)Cout)[(size_t)row * N + col] = v;
            }
        }
    }
}

// ---------------- Flash attention: qkv bf16 [B,S,3,H,HD] -> ctx bf16 [B,S,D] --------
// grid = B*H*(S/64); 4 waves/block, each wave owns a 16-row Q tile; 32-key KV tiles.
// K rows staged with kappa-permutation so swapped-QK^T output registers are already
// in canonical A-fragment order for the PV MFMA (no cross-lane rearrange needed).
__global__ __launch_bounds__(256) void attn_kernel(const u16* __restrict__ qkv,
                                                   u16* __restrict__ ctx) {
    int bid = blockIdx.x;
    int qt = bid & 15;
    int h  = (bid >> 4) & 15;
    int b  = bid >> 8;
    int tid = threadIdx.x, lane = tid & 63, w = tid >> 6;
    int q = lane & 15, g = lane >> 4;

    __shared__ u16 sQ[64 * 72];
    __shared__ u16 sK[32 * 72];
    __shared__ u16 sVT[64 * 36];

    const size_t tokBase = ((size_t)b * 1024) * 3072 + (size_t)h * 64;
    const float SC = 0.125f * 1.44269504088896f;  // HD^-0.5 * log2(e), softmax in exp2 domain

    #pragma unroll
    for (int p = 0; p < 2; p++) {
        int flat = (p * 256 + tid) * 8;
        int r = flat >> 6, c = flat & 63;
        uint4 v = *(const uint4*)(qkv + tokBase + (size_t)(qt * 64 + r) * 3072 + c);
        *(uint4*)(sQ + r * 72 + c) = v;
    }
    __syncthreads();
    bf16x8 qf0 = *(const bf16x8*)(sQ + (w * 16 + q) * 72 + g * 8);
    bf16x8 qf1 = *(const bf16x8*)(sQ + (w * 16 + q) * 72 + 32 + g * 8);

    float m_run = -1e30f, l_run = 0.0f;
    f32x4 o[4];
    #pragma unroll
    for (int n = 0; n < 4; n++) o[n] = (f32x4){0.f, 0.f, 0.f, 0.f};

    // staging indices
    int kr = tid >> 3, kc = (tid & 7) * 8;
    int kperm = ((kr >> 2) & 3) * 8 + (kr >> 4) * 4 + (kr & 3);  // kappa(kr)

    for (int kt = 0; kt < 32; kt++) {
        __syncthreads();
        {   // stage K tile [32][64], row kr holds global key kperm
            uint4 v = *(const uint4*)(qkv + tokBase + (size_t)(kt * 32 + kperm) * 3072 + 1024 + kc);
            *(uint4*)(sK + kr * 72 + kc) = v;
        }
        #pragma unroll
        for (int p = 0; p < 2; p++) {  // stage V^T [64][32], stride 36
            int flat = (p * 256 + tid) * 4;
            int key = flat >> 6, cc = flat & 63;
            ushort4 vv = *(const ushort4*)(qkv + tokBase + (size_t)(kt * 32 + key) * 3072 + 2048 + cc);
            sVT[(cc + 0) * 36 + key] = vv.x;
            sVT[(cc + 1) * 36 + key] = vv.y;
            sVT[(cc + 2) * 36 + key] = vv.z;
            sVT[(cc + 3) * 36 + key] = vv.w;
        }
        __syncthreads();

        // S' = K(32xHD) . Q^T  (swapped operands); lane(q,g) ends holding keys 8g..8g+7 of row q
        f32x4 s0 = (f32x4){0.f, 0.f, 0.f, 0.f}, s1 = s0;
        {
            bf16x8 k00 = *(const bf16x8*)(sK + (q) * 72 + g * 8);
            bf16x8 k01 = *(const bf16x8*)(sK + (q) * 72 + 32 + g * 8);
            s0 = __builtin_amdgcn_mfma_f32_16x16x32_bf16(k00, qf0, s0, 0, 0, 0);
            s0 = __builtin_amdgcn_mfma_f32_16x16x32_bf16(k01, qf1, s0, 0, 0, 0);
            bf16x8 k10 = *(const bf16x8*)(sK + (16 + q) * 72 + g * 8);
            bf16x8 k11 = *(const bf16x8*)(sK + (16 + q) * 72 + 32 + g * 8);
            s1 = __builtin_amdgcn_mfma_f32_16x16x32_bf16(k10, qf0, s1, 0, 0, 0);
            s1 = __builtin_amdgcn_mfma_f32_16x16x32_bf16(k11, qf1, s1, 0, 0, 0);
        }
        float ps[8];
        #pragma unroll
        for (int r = 0; r < 4; r++) { ps[r] = s0[r] * SC; ps[4 + r] = s1[r] * SC; }
        float tm = ps[0];
        #pragma unroll
        for (int i = 1; i < 8; i++) tm = fmaxf(tm, ps[i]);
        tm = fmaxf(tm, __shfl_xor(tm, 16, 64));
        tm = fmaxf(tm, __shfl_xor(tm, 32, 64));

        // defer-max (T13): only rescale when max grows by > 8 (exp2 domain)
        if (!__all(tm - m_run <= 8.0f)) {
            float nm = fmaxf(m_run, tm);
            float f = exp2f(m_run - nm);
            float fr[4];
            #pragma unroll
            for (int r = 0; r < 4; r++) fr[r] = __shfl(f, g * 4 + r, 64);
            #pragma unroll
            for (int n = 0; n < 4; n++)
                #pragma unroll
                for (int r = 0; r < 4; r++) o[n][r] *= fr[r];
            l_run *= f;
            m_run = nm;
        }

        float ts = 0.0f;
        #pragma unroll
        for (int i = 0; i < 8; i++) { ps[i] = exp2f(ps[i] - m_run); ts += ps[i]; }
        ts += __shfl_xor(ts, 16, 64);
        ts += __shfl_xor(ts, 32, 64);
        l_run += ts;

        // P already lane-local in A-frag order thanks to kappa staging
        bf16x8 pf;
        #pragma unroll
        for (int j = 0; j < 8; j++) pf[j] = (short)f2bf(ps[j]);

        // PV: one K=32 MFMA per 16-col block of HD
        #pragma unroll
        for (int n = 0; n < 4; n++) {
            bf16x4 vlo = *(const bf16x4*)(sVT + (n * 16 + q) * 36 + g * 8);
            bf16x4 vhi = *(const bf16x4*)(sVT + (n * 16 + q) * 36 + g * 8 + 4);
            bf16x8 vf;
            #pragma unroll
            for (int j = 0; j < 4; j++) { vf[j] = vlo[j]; vf[4 + j] = vhi[j]; }
            o[n] = __builtin_amdgcn_mfma_f32_16x16x32_bf16(pf, vf, o[n], 0, 0, 0);
        }
    }

    float inv = 1.0f / l_run;
    float ir[4];
    #pragma unroll
    for (int r = 0; r < 4; r++) ir[r] = __shfl(inv, g * 4 + r, 64);
    size_t outBase = ((size_t)b * 1024 + qt * 64 + w * 16) * 1024 + (size_t)h * 64;
    #pragma unroll
    for (int n = 0; n < 4; n++)
        #pragma unroll
        for (int r = 0; r < 4; r++)
            ctx[outBase + (size_t)(g * 4 + r) * 1024 + n * 16 + q] = f2bf(o[n][r] * ir[r]);
}

extern "C" void kernel_launch(void* const* d_in, const int* in_sizes, int n_in,
                              void* d_out, int out_size, void* d_ws, size_t ws_size,
                              hipStream_t stream) {
    const float* x      = (const float*)d_in[0];
    const float* qkv_w  = (const float*)d_in[1];
    const float* qkv_b  = (const float*)d_in[2];
    const float* proj_w = (const float*)d_in[3];
    const float* proj_b = (const float*)d_in[4];
    const float* fc1_w  = (const float*)d_in[5];
    const float* fc1_b  = (const float*)d_in[6];
    const float* fc2_w  = (const float*)d_in[7];
    const float* fc2_b  = (const float*)d_in[8];
    const float* ln1_g  = (const float*)d_in[9];
    const float* ln1_b  = (const float*)d_in[10];
    const float* ln2_g  = (const float*)d_in[11];
    const float* ln2_b  = (const float*)d_in[12];
    float* out = (float*)d_out;

    char* ws = (char*)d_ws;
    u16* wq = (u16*)(ws);               // qkv_w bf16: 3145728 elems
    u16* wp = (u16*)(ws + 6291456);     // proj_w bf16: 1048576
    u16* w1 = (u16*)(ws + 8388608);     // fc1_w bf16: 4194304
    u16* w2 = (u16*)(ws + 16777216);    // fc2_w bf16: 4194304
    char* pool = ws + 25165824;
    u16* hbuf = (u16*)(pool);                   // ln1 out bf16 [8192,1024]
    u16* qkvb = (u16*)(pool + 16777216);        // qkv bf16 [8192,3072]
    u16* ctxb = (u16*)(pool);                   // ctx bf16 (reuses hbuf, h dead)
    u16* h2b  = (u16*)(pool + 16777216);        // ln2 out bf16 (reuses qkv)
    u16* a1b  = (u16*)(pool + 33554432);        // gelu out bf16 [8192,4096]

    cvt_kernel<<<3072, 256, 0, stream>>>(qkv_w, wq, 786432);
    cvt_kernel<<<1024, 256, 0, stream>>>(proj_w, wp, 262144);
    cvt_kernel<<<4096, 256, 0, stream>>>(fc1_w, w1, 1048576);
    cvt_kernel<<<4096, 256, 0, stream>>>(fc2_w, w2, 1048576);

    ln_kernel<<<8192, 256, 0, stream>>>(x, ln1_g, ln1_b, hbuf);
    gemm_kernel<0,0,1><<<64 * 24, 256, 0, stream>>>(hbuf, wq, qkv_b, nullptr, qkvb, 8192, 3072, 1024);
    attn_kernel<<<2048, 256, 0, stream>>>(qkvb, ctxb);
    gemm_kernel<0,1,0><<<64 * 8, 256, 0, stream>>>(ctxb, wp, proj_b, x, out, 8192, 1024, 1024);
    ln_kernel<<<8192, 256, 0, stream>>>(out, ln2_g, ln2_b, h2b);
    gemm_kernel<1,0,1><<<64 * 32, 256, 0, stream>>>(h2b, w1, fc1_b, nullptr, a1b, 8192, 4096, 1024);
    gemm_kernel<0,1,0><<<64 * 8, 256, 0, stream>>>(a1b, w2, fc2_b, out, out, 8192, 1024, 4096);
}

// Round 3
// 563.230 us; speedup vs baseline: 1.1479x; 1.0495x over previous
//
#include <hip/hip_runtime.h>
#include <stdint.h>

typedef unsigned short u16;
typedef __attribute__((ext_vector_type(8))) short bf16x8;
typedef __attribute__((ext_vector_type(4))) short bf16x4;
typedef __attribute__((ext_vector_type(4))) float f32x4;

__device__ __forceinline__ u16 f2bf(float f) {
    union { float f; uint32_t u; } v; v.f = f;
    uint32_t r = (v.u + 0x7FFFu + ((v.u >> 16) & 1u)) >> 16;
    return (u16)r;
}

// async global->LDS, 16B per lane; lds base must be wave-uniform
__device__ __forceinline__ void g2l16(const u16* g, u16* l) {
    __builtin_amdgcn_global_load_lds(
        (const __attribute__((address_space(1))) uint32_t*)g,
        (__attribute__((address_space(3))) uint32_t*)l, 16, 0, 0);
}

// tanh-based GELU (abs err ~3e-4, fine vs 0.123 threshold; much cheaper than ocml erff)
__device__ __forceinline__ float gelu_f(float x) {
    float x2 = x * x;
    float u = x * (0.7978845608028654f + 0.035677408136300125f * x2);
    float t = exp2f(-2.8853900817779268f * fabsf(u));   // e^{-2|u|}
    float th = (1.0f - t) / (1.0f + t);                  // tanh(|u|)
    th = (u < 0.0f) ? -th : th;
    return 0.5f * x * (1.0f + th);
}

// ---------------- fp32 -> bf16 convert (weights) ----------------
__global__ __launch_bounds__(256) void cvt_kernel(const float* __restrict__ in,
                                                  u16* __restrict__ out, int n4) {
    int i = blockIdx.x * 256 + threadIdx.x;
    if (i < n4) {
        float4 v = ((const float4*)in)[i];
        uint2 o;
        o.x = (uint32_t)f2bf(v.x) | ((uint32_t)f2bf(v.y) << 16);
        o.y = (uint32_t)f2bf(v.z) | ((uint32_t)f2bf(v.w) << 16);
        ((uint2*)out)[i] = o;
    }
}

// ---------------- LayerNorm (fp32 in, bf16 out), D=1024 ----------------
__global__ __launch_bounds__(256) void ln_kernel(const float* __restrict__ x,
                                                 const float* __restrict__ g,
                                                 const float* __restrict__ beta,
                                                 u16* __restrict__ out) {
    int row = blockIdx.x;
    int tid = threadIdx.x;
    const float4 v = ((const float4*)(x + (size_t)row * 1024))[tid];
    float s  = v.x + v.y + v.z + v.w;
    float sq = v.x*v.x + v.y*v.y + v.z*v.z + v.w*v.w;
    #pragma unroll
    for (int off = 32; off; off >>= 1) {
        s  += __shfl_xor(s,  off, 64);
        sq += __shfl_xor(sq, off, 64);
    }
    __shared__ float rs[4], rq[4];
    int w = tid >> 6;
    if ((tid & 63) == 0) { rs[w] = s; rq[w] = sq; }
    __syncthreads();
    s  = rs[0] + rs[1] + rs[2] + rs[3];
    sq = rq[0] + rq[1] + rq[2] + rq[3];
    float mu   = s * (1.0f / 1024.0f);
    float var  = sq * (1.0f / 1024.0f) - mu * mu;
    float rstd = rsqrtf(var + 1e-6f);
    float4 gv = ((const float4*)g)[tid];
    float4 bv = ((const float4*)beta)[tid];
    uint2 o;
    o.x = (uint32_t)f2bf((v.x - mu) * rstd * gv.x + bv.x) |
          ((uint32_t)f2bf((v.y - mu) * rstd * gv.y + bv.y) << 16);
    o.y = (uint32_t)f2bf((v.z - mu) * rstd * gv.z + bv.z) |
          ((uint32_t)f2bf((v.w - mu) * rstd * gv.w + bv.w) << 16);
    ((uint2*)(out + (size_t)row * 1024))[tid] = o;
}

// ---------------- GEMM: C[M,N] = A[M,K](bf16) * W[N,K](bf16)^T + bias (+res)(+gelu) ----
// 2-phase 256-class template: BM = M_REP*32, BN = 256, BK = 64, 8 waves (2x4),
// double-buffered LDS, global_load_lds staging, one barrier per K-tile.
// T2 both-sides XOR swizzle: linear LDS dest + pre-swizzled global src col,
// same XOR on ds_read addr (col ^= (row&7)<<3 in elems; involution).
template<int M_REP, int ACT, int RES, int OUTBF>
__global__ __launch_bounds__(512, 2) void gemm2_kernel(
    const u16* __restrict__ A, const u16* __restrict__ W,
    const float* __restrict__ bias, const float* __restrict__ res,
    void* __restrict__ Cout, int M, int N, int K)
{
    const int BM = M_REP * 32;
    __shared__ u16 sA[2 * BM * 64];
    __shared__ u16 sB[2 * 256 * 64];

    int tid = threadIdx.x;
    int lane = tid & 63, wid = tid >> 6;
    int wm = wid >> 2, wn = wid & 3;      // 2 x 4 wave grid
    int q = lane & 15, g = lane >> 4;

    // bijective XCD chunk swizzle (grids are multiples of 8), column-major tiles
    int MT = M / BM;
    int nwg = gridDim.x;
    int chunk = nwg >> 3;
    int bid = blockIdx.x;
    int wg = (bid & 7) * chunk + (bid >> 3);
    int mt = wg % MT, nt = wg / MT;
    int m0 = mt * BM, n0 = nt * 256;

    const int NT = K >> 6;

    f32x4 acc[M_REP][4] = {};

    // staging addressing (per-round): dest elem off = idx*8 (linear), src col pre-swizzled
    auto STAGE = [&](int buf, int k0) {
        #pragma unroll
        for (int l = 0; l < BM / 64; l++) {
            int idx = l * 512 + tid;
            int row = idx >> 3;
            int col = ((idx & 7) * 8) ^ ((row & 7) << 3);
            g2l16(A + (size_t)(m0 + row) * K + k0 + col,
                  sA + buf * (BM * 64) + (l * 512 + wid * 64) * 8);
        }
        #pragma unroll
        for (int l = 0; l < 4; l++) {
            int idx = l * 512 + tid;
            int row = idx >> 3;
            int col = ((idx & 7) * 8) ^ ((row & 7) << 3);
            g2l16(W + (size_t)(n0 + row) * K + k0 + col,
                  sB + buf * (256 * 64) + (l * 512 + wid * 64) * 8);
        }
    };

    STAGE(0, 0);
    __syncthreads();

    int buf = 0;
    for (int t = 0; t < NT; t++) {
        if (t + 1 < NT) STAGE(buf ^ 1, (t + 1) << 6);
        const u16* bA = sA + buf * (BM * 64);
        const u16* bB = sB + buf * (256 * 64);
        #pragma unroll
        for (int ks = 0; ks < 2; ks++) {
            bf16x8 af[M_REP], bfr[4];
            #pragma unroll
            for (int i = 0; i < M_REP; i++) {
                int rowL = wm * (BM / 2) + i * 16 + q;
                int colE = (ks * 32 + g * 8) ^ ((rowL & 7) << 3);
                af[i] = *(const bf16x8*)(bA + rowL * 64 + colE);
            }
            #pragma unroll
            for (int j = 0; j < 4; j++) {
                int rowL = wn * 64 + j * 16 + q;
                int colE = (ks * 32 + g * 8) ^ ((rowL & 7) << 3);
                bfr[j] = *(const bf16x8*)(bB + rowL * 64 + colE);
            }
            #pragma unroll
            for (int i = 0; i < M_REP; i++)
                #pragma unroll
                for (int j = 0; j < 4; j++)
                    acc[i][j] = __builtin_amdgcn_mfma_f32_16x16x32_bf16(af[i], bfr[j], acc[i][j], 0, 0, 0);
        }
        __syncthreads();
        buf ^= 1;
    }

    #pragma unroll
    for (int i = 0; i < M_REP; i++) {
        #pragma unroll
        for (int j = 0; j < 4; j++) {
            int col = n0 + wn * 64 + j * 16 + q;
            float bz = bias[col];
            #pragma unroll
            for (int r = 0; r < 4; r++) {
                int row = m0 + wm * (BM / 2) + i * 16 + g * 4 + r;
                float v = acc[i][j][r] + bz;
                if (ACT == 1) v = gelu_f(v);
                if (RES) v += res[(size_t)row * N + col];
                if (OUTBF) ((u16*)Cout)[(size_t)row * N + col] = f2bf(v);
                else       ((float*)Cout)[(size_t)row * N + col] = v;
            }
        }
    }
}

// ---------------- Flash attention: qkv bf16 [B,S,3,H,HD] -> ctx bf16 [B,S,D] --------
__global__ __launch_bounds__(256) void attn_kernel(const u16* __restrict__ qkv,
                                                   u16* __restrict__ ctx) {
    int bid = blockIdx.x;
    int qt = bid & 15;
    int h  = (bid >> 4) & 15;
    int b  = bid >> 8;
    int tid = threadIdx.x, lane = tid & 63, w = tid >> 6;
    int q = lane & 15, g = lane >> 4;

    __shared__ u16 sQ[64 * 72];
    __shared__ u16 sK[32 * 72];
    __shared__ u16 sVT[64 * 36];

    const size_t tokBase = ((size_t)b * 1024) * 3072 + (size_t)h * 64;
    const float SC = 0.125f * 1.44269504088896f;  // HD^-0.5 * log2(e)

    #pragma unroll
    for (int p = 0; p < 2; p++) {
        int flat = (p * 256 + tid) * 8;
        int r = flat >> 6, c = flat & 63;
        uint4 v = *(const uint4*)(qkv + tokBase + (size_t)(qt * 64 + r) * 3072 + c);
        *(uint4*)(sQ + r * 72 + c) = v;
    }
    __syncthreads();
    bf16x8 qf0 = *(const bf16x8*)(sQ + (w * 16 + q) * 72 + g * 8);
    bf16x8 qf1 = *(const bf16x8*)(sQ + (w * 16 + q) * 72 + 32 + g * 8);

    float m_run = -1e30f, l_run = 0.0f;
    f32x4 o[4];
    #pragma unroll
    for (int n = 0; n < 4; n++) o[n] = (f32x4){0.f, 0.f, 0.f, 0.f};

    int kr = tid >> 3, kc = (tid & 7) * 8;
    int kperm = ((kr >> 2) & 3) * 8 + (kr >> 4) * 4 + (kr & 3);  // kappa(kr)

    for (int kt = 0; kt < 32; kt++) {
        __syncthreads();
        {   // stage K tile [32][64], row kr holds global key kperm
            uint4 v = *(const uint4*)(qkv + tokBase + (size_t)(kt * 32 + kperm) * 3072 + 1024 + kc);
            *(uint4*)(sK + kr * 72 + kc) = v;
        }
        #pragma unroll
        for (int p = 0; p < 2; p++) {  // stage V^T [64][32], stride 36
            int flat = (p * 256 + tid) * 4;
            int key = flat >> 6, cc = flat & 63;
            ushort4 vv = *(const ushort4*)(qkv + tokBase + (size_t)(kt * 32 + key) * 3072 + 2048 + cc);
            sVT[(cc + 0) * 36 + key] = vv.x;
            sVT[(cc + 1) * 36 + key] = vv.y;
            sVT[(cc + 2) * 36 + key] = vv.z;
            sVT[(cc + 3) * 36 + key] = vv.w;
        }
        __syncthreads();

        f32x4 s0 = (f32x4){0.f, 0.f, 0.f, 0.f}, s1 = s0;
        {
            bf16x8 k00 = *(const bf16x8*)(sK + (q) * 72 + g * 8);
            bf16x8 k01 = *(const bf16x8*)(sK + (q) * 72 + 32 + g * 8);
            s0 = __builtin_amdgcn_mfma_f32_16x16x32_bf16(k00, qf0, s0, 0, 0, 0);
            s0 = __builtin_amdgcn_mfma_f32_16x16x32_bf16(k01, qf1, s0, 0, 0, 0);
            bf16x8 k10 = *(const bf16x8*)(sK + (16 + q) * 72 + g * 8);
            bf16x8 k11 = *(const bf16x8*)(sK + (16 + q) * 72 + 32 + g * 8);
            s1 = __builtin_amdgcn_mfma_f32_16x16x32_bf16(k10, qf0, s1, 0, 0, 0);
            s1 = __builtin_amdgcn_mfma_f32_16x16x32_bf16(k11, qf1, s1, 0, 0, 0);
        }
        float ps[8];
        #pragma unroll
        for (int r = 0; r < 4; r++) { ps[r] = s0[r] * SC; ps[4 + r] = s1[r] * SC; }
        float tm = ps[0];
        #pragma unroll
        for (int i = 1; i < 8; i++) tm = fmaxf(tm, ps[i]);
        tm = fmaxf(tm, __shfl_xor(tm, 16, 64));
        tm = fmaxf(tm, __shfl_xor(tm, 32, 64));

        if (!__all(tm - m_run <= 8.0f)) {
            float nm = fmaxf(m_run, tm);
            float f = exp2f(m_run - nm);
            float fr[4];
            #pragma unroll
            for (int r = 0; r < 4; r++) fr[r] = __shfl(f, g * 4 + r, 64);
            #pragma unroll
            for (int n = 0; n < 4; n++)
                #pragma unroll
                for (int r = 0; r < 4; r++) o[n][r] *= fr[r];
            l_run *= f;
            m_run = nm;
        }

        float ts = 0.0f;
        #pragma unroll
        for (int i = 0; i < 8; i++) { ps[i] = exp2f(ps[i] - m_run); ts += ps[i]; }
        ts += __shfl_xor(ts, 16, 64);
        ts += __shfl_xor(ts, 32, 64);
        l_run += ts;

        bf16x8 pf;
        #pragma unroll
        for (int j = 0; j < 8; j++) pf[j] = (short)f2bf(ps[j]);

        #pragma unroll
        for (int n = 0; n < 4; n++) {
            bf16x4 vlo = *(const bf16x4*)(sVT + (n * 16 + q) * 36 + g * 8);
            bf16x4 vhi = *(const bf16x4*)(sVT + (n * 16 + q) * 36 + g * 8 + 4);
            bf16x8 vf;
            #pragma unroll
            for (int j = 0; j < 4; j++) { vf[j] = vlo[j]; vf[4 + j] = vhi[j]; }
            o[n] = __builtin_amdgcn_mfma_f32_16x16x32_bf16(pf, vf, o[n], 0, 0, 0);
        }
    }

    float inv = 1.0f / l_run;
    float ir[4];
    #pragma unroll
    for (int r = 0; r < 4; r++) ir[r] = __shfl(inv, g * 4 + r, 64);
    size_t outBase = ((size_t)b * 1024 + qt * 64 + w * 16) * 1024 + (size_t)h * 64;
    #pragma unroll
    for (int n = 0; n < 4; n++)
        #pragma unroll
        for (int r = 0; r < 4; r++)
            ctx[outBase + (size_t)(g * 4 + r) * 1024 + n * 16 + q] = f2bf(o[n][r] * ir[r]);
}

extern "C" void kernel_launch(void* const* d_in, const int* in_sizes, int n_in,
                              void* d_out, int out_size, void* d_ws, size_t ws_size,
                              hipStream_t stream) {
    const float* x      = (const float*)d_in[0];
    const float* qkv_w  = (const float*)d_in[1];
    const float* qkv_b  = (const float*)d_in[2];
    const float* proj_w = (const float*)d_in[3];
    const float* proj_b = (const float*)d_in[4];
    const float* fc1_w  = (const float*)d_in[5];
    const float* fc1_b  = (const float*)d_in[6];
    const float* fc2_w  = (const float*)d_in[7];
    const float* fc2_b  = (const float*)d_in[8];
    const float* ln1_g  = (const float*)d_in[9];
    const float* ln1_b  = (const float*)d_in[10];
    const float* ln2_g  = (const float*)d_in[11];
    const float* ln2_b  = (const float*)d_in[12];
    float* out = (float*)d_out;

    char* ws = (char*)d_ws;
    u16* wq = (u16*)(ws);               // qkv_w bf16: 3145728 elems
    u16* wp = (u16*)(ws + 6291456);     // proj_w bf16: 1048576
    u16* w1 = (u16*)(ws + 8388608);     // fc1_w bf16: 4194304
    u16* w2 = (u16*)(ws + 16777216);    // fc2_w bf16: 4194304
    char* pool = ws + 25165824;
    u16* hbuf = (u16*)(pool);                   // ln1 out bf16 [8192,1024]
    u16* qkvb = (u16*)(pool + 16777216);        // qkv bf16 [8192,3072]
    u16* ctxb = (u16*)(pool);                   // ctx bf16 (reuses hbuf)
    u16* h2b  = (u16*)(pool + 16777216);        // ln2 out bf16 (reuses qkv)
    u16* a1b  = (u16*)(pool + 33554432);        // gelu out bf16 [8192,4096]

    cvt_kernel<<<3072, 256, 0, stream>>>(qkv_w, wq, 786432);
    cvt_kernel<<<1024, 256, 0, stream>>>(proj_w, wp, 262144);
    cvt_kernel<<<4096, 256, 0, stream>>>(fc1_w, w1, 1048576);
    cvt_kernel<<<4096, 256, 0, stream>>>(fc2_w, w2, 1048576);

    ln_kernel<<<8192, 256, 0, stream>>>(x, ln1_g, ln1_b, hbuf);
    // qkv: M=8192 N=3072 K=1024, 128x256 tiles -> 768 blocks (3 full GPU waves)
    gemm2_kernel<4,0,0,1><<<768, 512, 0, stream>>>(hbuf, wq, qkv_b, nullptr, qkvb, 8192, 3072, 1024);
    attn_kernel<<<2048, 256, 0, stream>>>(qkvb, ctxb);
    // proj: N=1024, 128x256 tiles -> 256 blocks
    gemm2_kernel<4,0,1,0><<<256, 512, 0, stream>>>(ctxb, wp, proj_b, x, out, 8192, 1024, 1024);
    ln_kernel<<<8192, 256, 0, stream>>>(out, ln2_g, ln2_b, h2b);
    // fc1: N=4096, 256x256 tiles -> 512 blocks (2 full GPU waves)
    gemm2_kernel<8,1,0,1><<<512, 512, 0, stream>>>(h2b, w1, fc1_b, nullptr, a1b, 8192, 4096, 1024);
    // fc2: N=1024 K=4096, 128x256 tiles -> 256 blocks
    gemm2_kernel<4,0,1,0><<<256, 512, 0, stream>>>(a1b, w2, fc2_b, out, out, 8192, 1024, 4096);
}

// Round 4
// 529.999 us; speedup vs baseline: 1.2199x; 1.0627x over previous
//
#include <hip/hip_runtime.h>
#include <stdint.h>

typedef unsigned short u16;
typedef __attribute__((ext_vector_type(8))) short bf16x8;
typedef __attribute__((ext_vector_type(4))) float f32x4;

__device__ __forceinline__ u16 f2bf(float f) {
    union { float f; uint32_t u; } v; v.f = f;
    uint32_t r = (v.u + 0x7FFFu + ((v.u >> 16) & 1u)) >> 16;
    return (u16)r;
}

// async global->LDS, 16B per lane; lds base must be wave-uniform
__device__ __forceinline__ void g2l16(const u16* g, u16* l) {
    __builtin_amdgcn_global_load_lds(
        (const __attribute__((address_space(1))) uint32_t*)g,
        (__attribute__((address_space(3))) uint32_t*)l, 16, 0, 0);
}

// tanh-based GELU (abs err ~3e-4 vs exact erf; threshold is 0.123)
__device__ __forceinline__ float gelu_f(float x) {
    float x2 = x * x;
    float u = x * (0.7978845608028654f + 0.035677408136300125f * x2);
    float t = exp2f(-2.8853900817779268f * fabsf(u));   // e^{-2|u|}
    float th = (1.0f - t) / (1.0f + t);
    th = (u < 0.0f) ? -th : th;
    return 0.5f * x * (1.0f + th);
}

// ---------------- fp32 -> bf16 convert (weights) ----------------
__global__ __launch_bounds__(256) void cvt_kernel(const float* __restrict__ in,
                                                  u16* __restrict__ out, int n4) {
    int i = blockIdx.x * 256 + threadIdx.x;
    if (i < n4) {
        float4 v = ((const float4*)in)[i];
        uint2 o;
        o.x = (uint32_t)f2bf(v.x) | ((uint32_t)f2bf(v.y) << 16);
        o.y = (uint32_t)f2bf(v.z) | ((uint32_t)f2bf(v.w) << 16);
        ((uint2*)out)[i] = o;
    }
}

// ---------------- LayerNorm (fp32 in, bf16 out), D=1024 ----------------
__global__ __launch_bounds__(256) void ln_kernel(const float* __restrict__ x,
                                                 const float* __restrict__ g,
                                                 const float* __restrict__ beta,
                                                 u16* __restrict__ out) {
    int row = blockIdx.x;
    int tid = threadIdx.x;
    const float4 v = ((const float4*)(x + (size_t)row * 1024))[tid];
    float s  = v.x + v.y + v.z + v.w;
    float sq = v.x*v.x + v.y*v.y + v.z*v.z + v.w*v.w;
    #pragma unroll
    for (int off = 32; off; off >>= 1) {
        s  += __shfl_xor(s,  off, 64);
        sq += __shfl_xor(sq, off, 64);
    }
    __shared__ float rs[4], rq[4];
    int w = tid >> 6;
    if ((tid & 63) == 0) { rs[w] = s; rq[w] = sq; }
    __syncthreads();
    s  = rs[0] + rs[1] + rs[2] + rs[3];
    sq = rq[0] + rq[1] + rq[2] + rq[3];
    float mu   = s * (1.0f / 1024.0f);
    float var  = sq * (1.0f / 1024.0f) - mu * mu;
    float rstd = rsqrtf(var + 1e-6f);
    float4 gv = ((const float4*)g)[tid];
    float4 bv = ((const float4*)beta)[tid];
    uint2 o;
    o.x = (uint32_t)f2bf((v.x - mu) * rstd * gv.x + bv.x) |
          ((uint32_t)f2bf((v.y - mu) * rstd * gv.y + bv.y) << 16);
    o.y = (uint32_t)f2bf((v.z - mu) * rstd * gv.z + bv.z) |
          ((uint32_t)f2bf((v.w - mu) * rstd * gv.w + bv.w) << 16);
    ((uint2*)(out + (size_t)row * 1024))[tid] = o;
}

// ---------------- GEMM: C[M,N] = A[M,K](bf16) * W[N,K](bf16)^T + bias (+res)(+gelu) ----
// 128x256 tile, BK=64, 8 waves (2x4), double-buffered LDS, global_load_lds staging,
// counted-vmcnt 2-deep pipeline (T4): reads->regs, lgkm(0)+bar, STAGE(t+2) into
// consumed buf, MFMA, vmcnt(6) [t+1 landed, t+2 in flight], bar.
// T2 both-sides XOR swizzle on LDS (linear dest + pre-swizzled src col + same XOR on read).
// OUTMODE: 0=f32, 1=bf16, 2=qkv-split (cols<2048 -> Cout stride 2048; V cols -> vtb transposed)
template<int ACT, int RES, int OUTMODE>
__global__ __launch_bounds__(512) void gemm2_kernel(
    const u16* __restrict__ A, const u16* __restrict__ W,
    const float* __restrict__ bias, const float* __restrict__ res,
    void* __restrict__ Cout, u16* __restrict__ vtb, int M, int N, int K)
{
    const int BM = 128, BN = 256, BK = 64;
    __shared__ u16 sA[2 * BM * BK];
    __shared__ u16 sB[2 * BN * BK];

    int tid = threadIdx.x;
    int lane = tid & 63, wid = tid >> 6;
    int wm = wid >> 2, wn = wid & 3;      // 2 x 4 wave grid
    int q = lane & 15, g = lane >> 4;

    int MT = M >> 7;
    int nwg = gridDim.x;
    int chunk = nwg >> 3;
    int bid = blockIdx.x;
    int wg = (bid & 7) * chunk + (bid >> 3);     // bijective XCD swizzle (nwg%8==0)
    int mt = wg % MT, nt = wg / MT;
    int m0 = mt << 7, n0 = nt << 8;
    const int NT = K >> 6;

    // per-thread staging sources (k=0) and wave-uniform LDS dests
    const u16* srcA[2]; const u16* srcB[4];
    u16* dstA[2]; u16* dstB[4];
    #pragma unroll
    for (int l = 0; l < 2; l++) {
        int idx = l * 512 + tid, row = idx >> 3;
        int col = ((idx & 7) * 8) ^ ((row & 7) << 3);
        srcA[l] = A + (size_t)(m0 + row) * K + col;
        dstA[l] = sA + (l * 512 + wid * 64) * 8;
    }
    #pragma unroll
    for (int l = 0; l < 4; l++) {
        int idx = l * 512 + tid, row = idx >> 3;
        int col = ((idx & 7) * 8) ^ ((row & 7) << 3);
        srcB[l] = W + (size_t)(n0 + row) * K + col;
        dstB[l] = sB + (l * 512 + wid * 64) * 8;
    }

    // 6 vm-ops per STAGE per wave
    #define STAGE(bf, t) { int ko = (t) * 64; int boA = (bf) * (BM * BK); int boB = (bf) * (BN * BK); \
        g2l16(srcA[0] + ko, dstA[0] + boA); g2l16(srcA[1] + ko, dstA[1] + boA); \
        g2l16(srcB[0] + ko, dstB[0] + boB); g2l16(srcB[1] + ko, dstB[1] + boB); \
        g2l16(srcB[2] + ko, dstB[2] + boB); g2l16(srcB[3] + ko, dstB[3] + boB); }

    f32x4 acc[4][4] = {};

    STAGE(0, 0);
    STAGE(1, 1);
    asm volatile("s_waitcnt vmcnt(6)\n" ::: "memory");   // tile 0 landed
    __builtin_amdgcn_s_barrier();

    int buf = 0;
    for (int t = 0; t < NT; t++) {
        const u16* bA = sA + buf * (BM * BK);
        const u16* bB = sB + buf * (BN * BK);
        bf16x8 af[2][4], bfr[2][4];
        #pragma unroll
        for (int ks = 0; ks < 2; ks++) {
            #pragma unroll
            for (int i = 0; i < 4; i++) {
                int rowL = wm * 64 + i * 16 + q;
                int colE = (ks * 32 + g * 8) ^ ((rowL & 7) << 3);
                af[ks][i] = *(const bf16x8*)(bA + rowL * 64 + colE);
            }
            #pragma unroll
            for (int j = 0; j < 4; j++) {
                int rowL = wn * 64 + j * 16 + q;
                int colE = (ks * 32 + g * 8) ^ ((rowL & 7) << 3);
                bfr[ks][j] = *(const bf16x8*)(bB + rowL * 64 + colE);
            }
        }
        asm volatile("s_waitcnt lgkmcnt(0)\n" ::: "memory");  // my reads done
        __builtin_amdgcn_s_barrier();                          // everyone's reads done
        bool pre = (t + 2 < NT);
        if (pre) STAGE(buf, t + 2);                            // overwrite consumed buf
        #pragma unroll
        for (int ks = 0; ks < 2; ks++)
            #pragma unroll
            for (int i = 0; i < 4; i++)
                #pragma unroll
                for (int j = 0; j < 4; j++)
                    acc[i][j] = __builtin_amdgcn_mfma_f32_16x16x32_bf16(af[ks][i], bfr[ks][j], acc[i][j], 0, 0, 0);
        if (pre) { asm volatile("s_waitcnt vmcnt(6)\n" ::: "memory"); }  // t+1 landed, t+2 flying
        else     { asm volatile("s_waitcnt vmcnt(0)\n" ::: "memory"); }
        __builtin_amdgcn_s_barrier();
        buf ^= 1;
    }
    #undef STAGE

    #pragma unroll
    for (int i = 0; i < 4; i++) {
        #pragma unroll
        for (int j = 0; j < 4; j++) {
            int col = n0 + wn * 64 + j * 16 + q;
            float bz = bias[col];
            int row0 = m0 + wm * 64 + i * 16 + g * 4;
            float vv[4];
            #pragma unroll
            for (int r = 0; r < 4; r++) {
                float v = acc[i][j][r] + bz;
                if (ACT == 1) v = gelu_f(v);
                if (RES) v += res[(size_t)(row0 + r) * N + col];
                vv[r] = v;
            }
            if (OUTMODE == 0) {
                #pragma unroll
                for (int r = 0; r < 4; r++) ((float*)Cout)[(size_t)(row0 + r) * N + col] = vv[r];
            } else if (OUTMODE == 1) {
                #pragma unroll
                for (int r = 0; r < 4; r++) ((u16*)Cout)[(size_t)(row0 + r) * N + col] = f2bf(vv[r]);
            } else {
                if (col < 2048) {   // Q,K -> [row][2048]
                    #pragma unroll
                    for (int r = 0; r < 4; r++) ((u16*)Cout)[(size_t)(row0 + r) * 2048 + col] = f2bf(vv[r]);
                } else {            // V -> transposed vtb[B][H][64][1024]
                    int hd = col & 63, hh = (col >> 6) - 32;
                    int b_ = row0 >> 10, s_ = row0 & 1023;
                    ushort4 pk = { f2bf(vv[0]), f2bf(vv[1]), f2bf(vv[2]), f2bf(vv[3]) };
                    *(ushort4*)(vtb + (((size_t)(b_ * 16 + hh) * 64 + hd) << 10) + s_) = pk;
                }
            }
        }
    }
}

// ---------------- Flash attention ----------------
// qk bf16 [B,S,2,H,64] (stride 2048), vt bf16 [B,H,64,S] -> ctx bf16 [B,S,D]
// grid = B*H*(S/64); 4 waves, each owns 16 q-rows; 64-key double-buffered tiles,
// one barrier per tile. kappa-staged K so swapped-QK^T lands P in A-frag order.
__global__ __launch_bounds__(256) void attn_kernel(const u16* __restrict__ qk,
                                                   const u16* __restrict__ vt,
                                                   u16* __restrict__ ctx) {
    int bid = blockIdx.x;
    int qt = bid & 15;
    int h  = (bid >> 4) & 15;
    int b  = bid >> 8;
    int tid = threadIdx.x, lane = tid & 63, w = tid >> 6;
    int q = lane & 15, g = lane >> 4;

    __shared__ u16 sK[2][64 * 72];
    __shared__ u16 sV[2][64 * 72];

    const size_t tokBase = (size_t)b * 1024 * 2048 + (size_t)h * 64;
    const u16* vbase = vt + (size_t)(b * 16 + h) * 64 * 1024;
    const float SC = 0.125f * 1.44269504088896f;  // HD^-0.5 * log2(e)

    // Q direct to registers
    const u16* qrow = qk + tokBase + (size_t)(qt * 64 + w * 16 + q) * 2048;
    bf16x8 qf0 = *(const bf16x8*)(qrow + g * 8);
    bf16x8 qf1 = *(const bf16x8*)(qrow + 32 + g * 8);

    // staging indices: 2 rows per thread (r0, 32+r0), 8 cols each
    int r0 = tid >> 3, c0 = (tid & 7) * 8;
    int kp0 = 8 * ((r0 >> 2) & 3) + 4 * ((r0 >> 4) & 1) + (r0 & 3);  // kappa(r0)
    int kp1 = 32 + kp0;                                               // kappa(32+r0)

    {   // prologue: stage tile 0
        uint4 k0 = *(const uint4*)(qk + tokBase + (size_t)kp0 * 2048 + 1024 + c0);
        uint4 k1 = *(const uint4*)(qk + tokBase + (size_t)kp1 * 2048 + 1024 + c0);
        uint4 v0 = *(const uint4*)(vbase + (size_t)r0 * 1024 + c0);
        uint4 v1 = *(const uint4*)(vbase + (size_t)(32 + r0) * 1024 + c0);
        *(uint4*)(&sK[0][r0 * 72 + c0]) = k0;
        *(uint4*)(&sK[0][(32 + r0) * 72 + c0]) = k1;
        *(uint4*)(&sV[0][r0 * 72 + c0]) = v0;
        *(uint4*)(&sV[0][(32 + r0) * 72 + c0]) = v1;
    }
    __syncthreads();

    float m_run = -1e30f, l_run = 0.0f;
    f32x4 o[4];
    #pragma unroll
    for (int n = 0; n < 4; n++) o[n] = (f32x4){0.f, 0.f, 0.f, 0.f};

    for (int kt = 0; kt < 16; kt++) {
        int cur = kt & 1;
        // prefetch next tile global->reg (latency hidden under QK + softmax)
        uint4 kn0 = {}, kn1 = {}, vn0 = {}, vn1 = {};
        if (kt < 15) {
            size_t kb = tokBase + (size_t)((kt + 1) * 64) * 2048 + 1024 + c0;
            kn0 = *(const uint4*)(qk + kb + (size_t)kp0 * 2048);
            kn1 = *(const uint4*)(qk + kb + (size_t)kp1 * 2048);
            vn0 = *(const uint4*)(vbase + (size_t)r0 * 1024 + (kt + 1) * 64 + c0);
            vn1 = *(const uint4*)(vbase + (size_t)(32 + r0) * 1024 + (kt + 1) * 64 + c0);
        }

        // QK^T: 4 key-subtiles x 2 dim-halves (swapped operands)
        f32x4 s[4];
        #pragma unroll
        for (int c = 0; c < 4; c++) {
            s[c] = (f32x4){0.f, 0.f, 0.f, 0.f};
            bf16x8 a0 = *(const bf16x8*)(&sK[cur][(c * 16 + q) * 72 + g * 8]);
            bf16x8 a1 = *(const bf16x8*)(&sK[cur][(c * 16 + q) * 72 + 32 + g * 8]);
            s[c] = __builtin_amdgcn_mfma_f32_16x16x32_bf16(a0, qf0, s[c], 0, 0, 0);
            s[c] = __builtin_amdgcn_mfma_f32_16x16x32_bf16(a1, qf1, s[c], 0, 0, 0);
        }
        // lane(q,g): ps[c*4+r] = score[key] with keys: c0:8g+r c1:8g+4+r c2:32+8g+r c3:32+8g+4+r
        float ps[16];
        #pragma unroll
        for (int c = 0; c < 4; c++)
            #pragma unroll
            for (int r = 0; r < 4; r++) ps[c * 4 + r] = s[c][r] * SC;

        float tm = ps[0];
        #pragma unroll
        for (int i = 1; i < 16; i++) tm = fmaxf(tm, ps[i]);
        tm = fmaxf(tm, __shfl_xor(tm, 16, 64));
        tm = fmaxf(tm, __shfl_xor(tm, 32, 64));

        if (!__all(tm - m_run <= 8.0f)) {   // defer-max (T13)
            float nm = fmaxf(m_run, tm);
            float f = exp2f(m_run - nm);
            float fr[4];
            #pragma unroll
            for (int r = 0; r < 4; r++) fr[r] = __shfl(f, g * 4 + r, 64);
            #pragma unroll
            for (int n = 0; n < 4; n++)
                #pragma unroll
                for (int r = 0; r < 4; r++) o[n][r] *= fr[r];
            l_run *= f;
            m_run = nm;
        }

        float ts = 0.0f;
        #pragma unroll
        for (int i = 0; i < 16; i++) { ps[i] = exp2f(ps[i] - m_run); ts += ps[i]; }
        ts += __shfl_xor(ts, 16, 64);
        ts += __shfl_xor(ts, 32, 64);
        l_run += ts;

        // P chunks already in canonical A-frag order (kappa staging)
        bf16x8 pf0, pf1;
        #pragma unroll
        for (int j = 0; j < 4; j++) {
            pf0[j]     = (short)f2bf(ps[j]);          // keys 8g+j
            pf0[4 + j] = (short)f2bf(ps[4 + j]);      // keys 8g+4+j
            pf1[j]     = (short)f2bf(ps[8 + j]);      // keys 32+8g+j
            pf1[4 + j] = (short)f2bf(ps[12 + j]);     // keys 32+8g+4+j
        }

        // write next tile into other buffer (no conflict with current readers)
        if (kt < 15) {
            *(uint4*)(&sK[cur ^ 1][r0 * 72 + c0]) = kn0;
            *(uint4*)(&sK[cur ^ 1][(32 + r0) * 72 + c0]) = kn1;
            *(uint4*)(&sV[cur ^ 1][r0 * 72 + c0]) = vn0;
            *(uint4*)(&sV[cur ^ 1][(32 + r0) * 72 + c0]) = vn1;
        }

        // PV: B-frag lane(q,g) = VT[n*16+q][key g*8+j (+32)]
        #pragma unroll
        for (int n = 0; n < 4; n++) {
            bf16x8 v0 = *(const bf16x8*)(&sV[cur][(n * 16 + q) * 72 + g * 8]);
            o[n] = __builtin_amdgcn_mfma_f32_16x16x32_bf16(pf0, v0, o[n], 0, 0, 0);
        }
        #pragma unroll
        for (int n = 0; n < 4; n++) {
            bf16x8 v1 = *(const bf16x8*)(&sV[cur][(n * 16 + q) * 72 + 32 + g * 8]);
            o[n] = __builtin_amdgcn_mfma_f32_16x16x32_bf16(pf1, v1, o[n], 0, 0, 0);
        }
        __syncthreads();
    }

    float inv = 1.0f / l_run;
    float ir[4];
    #pragma unroll
    for (int r = 0; r < 4; r++) ir[r] = __shfl(inv, g * 4 + r, 64);
    size_t outBase = ((size_t)b * 1024 + qt * 64 + w * 16) * 1024 + (size_t)h * 64;
    #pragma unroll
    for (int n = 0; n < 4; n++)
        #pragma unroll
        for (int r = 0; r < 4; r++)
            ctx[outBase + (size_t)(g * 4 + r) * 1024 + n * 16 + q] = f2bf(o[n][r] * ir[r]);
}

extern "C" void kernel_launch(void* const* d_in, const int* in_sizes, int n_in,
                              void* d_out, int out_size, void* d_ws, size_t ws_size,
                              hipStream_t stream) {
    const float* x      = (const float*)d_in[0];
    const float* qkv_w  = (const float*)d_in[1];
    const float* qkv_b  = (const float*)d_in[2];
    const float* proj_w = (const float*)d_in[3];
    const float* proj_b = (const float*)d_in[4];
    const float* fc1_w  = (const float*)d_in[5];
    const float* fc1_b  = (const float*)d_in[6];
    const float* fc2_w  = (const float*)d_in[7];
    const float* fc2_b  = (const float*)d_in[8];
    const float* ln1_g  = (const float*)d_in[9];
    const float* ln1_b  = (const float*)d_in[10];
    const float* ln2_g  = (const float*)d_in[11];
    const float* ln2_b  = (const float*)d_in[12];
    float* out = (float*)d_out;

    char* ws = (char*)d_ws;
    u16* wq = (u16*)(ws);               // qkv_w bf16
    u16* wp = (u16*)(ws + 6291456);     // proj_w bf16
    u16* w1 = (u16*)(ws + 8388608);     // fc1_w bf16
    u16* w2 = (u16*)(ws + 16777216);    // fc2_w bf16
    char* pool = ws + 25165824;
    u16* hbuf = (u16*)(pool);                   // ln1 out bf16 [8192,1024]   (0..16M)
    u16* qkb  = (u16*)(pool + 16777216);        // Q,K bf16 [8192,2048]       (16..48M)
    u16* vtb  = (u16*)(pool + 50331648);        // V^T bf16 [8,16,64,1024]    (48..64M)
    u16* ctxb = (u16*)(pool);                   // ctx bf16 (reuses hbuf)
    u16* h2b  = (u16*)(pool + 16777216);        // ln2 out (reuses qkb, dead)
    u16* a1b  = (u16*)(pool + 33554432);        // gelu out bf16 [8192,4096]  (32..96M)

    cvt_kernel<<<3072, 256, 0, stream>>>(qkv_w, wq, 786432);
    cvt_kernel<<<1024, 256, 0, stream>>>(proj_w, wp, 262144);
    cvt_kernel<<<4096, 256, 0, stream>>>(fc1_w, w1, 1048576);
    cvt_kernel<<<4096, 256, 0, stream>>>(fc2_w, w2, 1048576);

    ln_kernel<<<8192, 256, 0, stream>>>(x, ln1_g, ln1_b, hbuf);
    // qkv: M=8192 N=3072 K=1024 -> 64x12 = 768 blocks; Q,K->qkb, V->vtb transposed
    gemm2_kernel<0,0,2><<<768, 512, 0, stream>>>(hbuf, wq, qkv_b, nullptr, qkb, vtb, 8192, 3072, 1024);
    attn_kernel<<<2048, 256, 0, stream>>>(qkb, vtb, ctxb);
    // proj: 64x4 = 256 blocks
    gemm2_kernel<0,1,0><<<256, 512, 0, stream>>>(ctxb, wp, proj_b, x, out, nullptr, 8192, 1024, 1024);
    ln_kernel<<<8192, 256, 0, stream>>>(out, ln2_g, ln2_b, h2b);
    // fc1: 64x16 = 1024 blocks
    gemm2_kernel<1,0,1><<<1024, 512, 0, stream>>>(h2b, w1, fc1_b, nullptr, a1b, nullptr, 8192, 4096, 1024);
    // fc2: K=4096 -> 64x4 = 256 blocks
    gemm2_kernel<0,1,0><<<256, 512, 0, stream>>>(a1b, w2, fc2_b, out, out, nullptr, 8192, 1024, 4096);
}